// Round 4
// baseline (2811.194 us; speedup 1.0000x reference)
//
#include <hip/hip_runtime.h>

#define N_NODES 100000
#define N_EDGES 1600000
#define NBINS 1563   // ceil(N_NODES/64)

typedef __attribute__((ext_vector_type(8))) short bf16x8;
typedef __attribute__((ext_vector_type(4))) float f32x4;

__device__ __forceinline__ unsigned int f2bf(float f) {
    unsigned int u = __float_as_uint(f);
    u += 0x7fffu + ((u >> 16) & 1u);     // RNE (finite normals)
    return u >> 16;
}

// ---------------- weight convert+transpose: Wt[n][k] = bf16(W[k][n]) ----------------
__global__ __launch_bounds__(256)
void conv_w(const float* __restrict__ W1, const float* __restrict__ W2,
            unsigned short* __restrict__ W1t, unsigned short* __restrict__ W2t)
{
    int idx = blockIdx.x * 256 + threadIdx.x;
    if (idx < 256 * 128) {
        int k = idx >> 7, n = idx & 127;
        W1t[(size_t)n * 256 + k] = (unsigned short)f2bf(W1[idx]);
    } else if (idx < 256 * 128 + 128 * 128) {
        int j = idx - 256 * 128;
        int k = j >> 7, n = j & 127;
        W2t[(size_t)n * 128 + k] = (unsigned short)f2bf(W2[j]);
    }
}

// ---------------- MFMA GEMM: C[M x 128] = A[M x K] @ W[K x 128] + bias, C bf16 ----------------
template<int K, bool ABF16>
__global__ __launch_bounds__(256, 3)
void gemm_mfma(const void* __restrict__ Av, const unsigned short* __restrict__ Wt,
               const float* __restrict__ bias, unsigned short* __restrict__ C, int M)
{
    constexpr int BK = 64;
    constexpr int PK = BK + 8;                 // 144 B pitch: 2-way banks max (free)
    __shared__ unsigned short As[128 * PK];
    __shared__ unsigned short Bs[128 * PK];

    const int t    = threadIdx.x;
    const int m0   = blockIdx.x * 128;
    const int lane = t & 63;
    const int wv   = t >> 6;
    const int wm   = (wv >> 1) * 64;
    const int wn   = (wv & 1) * 64;
    const int l15  = lane & 15;
    const int quad = lane >> 4;

    f32x4 acc[4][4] = {};

    for (int k0 = 0; k0 < K; k0 += BK) {
        if (!ABF16) {
            const float* A = (const float*)Av;
            #pragma unroll
            for (int p = 0; p < 8; ++p) {
                int q  = p * 256 + t;
                int m  = q >> 4;
                int kq = (q & 15) << 2;
                int gm = m0 + m; if (gm >= M) gm = M - 1;
                float4 v = *(const float4*)(A + (size_t)gm * K + k0 + kq);
                unsigned int p0 = (f2bf(v.y) << 16) | f2bf(v.x);
                unsigned int p1 = (f2bf(v.w) << 16) | f2bf(v.z);
                *(uint2*)&As[m * PK + kq] = make_uint2(p0, p1);
            }
        } else {
            const unsigned short* A = (const unsigned short*)Av;
            #pragma unroll
            for (int p = 0; p < 4; ++p) {
                int q = p * 256 + t;
                int m = q >> 3;
                int g = q & 7;
                int gm = m0 + m; if (gm >= M) gm = M - 1;
                int4 v = *(const int4*)(A + (size_t)gm * K + k0 + g * 8);
                *(int4*)&As[m * PK + g * 8] = v;
            }
        }
        #pragma unroll
        for (int p = 0; p < 4; ++p) {
            int q = p * 256 + t;
            int n = q >> 3;
            int g = q & 7;
            int4 v = *(const int4*)(Wt + (size_t)n * K + k0 + g * 8);
            *(int4*)&Bs[n * PK + g * 8] = v;
        }
        __syncthreads();
        #pragma unroll
        for (int kk = 0; kk < BK; kk += 32) {
            bf16x8 a[4], b[4];
            #pragma unroll
            for (int i = 0; i < 4; ++i)
                a[i] = *(const bf16x8*)&As[(wm + i * 16 + l15) * PK + kk + quad * 8];
            #pragma unroll
            for (int j = 0; j < 4; ++j)
                b[j] = *(const bf16x8*)&Bs[(wn + j * 16 + l15) * PK + kk + quad * 8];
            #pragma unroll
            for (int i = 0; i < 4; ++i)
                #pragma unroll
                for (int j = 0; j < 4; ++j)
                    acc[i][j] = __builtin_amdgcn_mfma_f32_16x16x32_bf16(a[i], b[j], acc[i][j], 0, 0, 0);
        }
        __syncthreads();
    }

    float bv[4];
    #pragma unroll
    for (int j = 0; j < 4; ++j) bv[j] = bias[wn + j * 16 + l15];
    #pragma unroll
    for (int i = 0; i < 4; ++i) {
        #pragma unroll
        for (int r = 0; r < 4; ++r) {
            int gm = m0 + wm + i * 16 + quad * 4 + r;
            if (gm < M) {
                #pragma unroll
                for (int j = 0; j < 4; ++j)
                    C[(size_t)gm * 128 + wn + j * 16 + l15] =
                        (unsigned short)f2bf(acc[i][j][r] + bv[j]);
            }
        }
    }
}

// ---------------- bin histogram (bin = row>>6), per-block LDS ----------------
__global__ __launch_bounds__(256)
void bin_hist(const int* __restrict__ row, int* __restrict__ bincnt, int E)
{
    __shared__ int h[NBINS];
    int t = threadIdx.x;
    for (int i = t; i < NBINS; i += 256) h[i] = 0;
    __syncthreads();
    for (int e = blockIdx.x * 256 + t; e < E; e += gridDim.x * 256)
        atomicAdd(&h[row[e] >> 6], 1);
    __syncthreads();
    for (int i = t; i < NBINS; i += 256) {
        int v = h[i];
        if (v) atomicAdd(&bincnt[i], v);
    }
}

// ---------------- exclusive scan over NBINS (single block) ----------------
__global__ __launch_bounds__(256)
void bin_scan(const int* __restrict__ bincnt, int* __restrict__ binptr,
              int* __restrict__ cursor, int E)
{
    __shared__ int sd[256];
    const int PER = (NBINS + 255) / 256;   // 7
    int t = threadIdx.x;
    int v[PER]; int run = 0;
    #pragma unroll
    for (int j = 0; j < PER; ++j) {
        int idx = t * PER + j;
        int c = (idx < NBINS) ? bincnt[idx] : 0;
        v[j] = run; run += c;
    }
    sd[t] = run;
    __syncthreads();
    for (int off = 1; off < 256; off <<= 1) {
        int x = (t >= off) ? sd[t - off] : 0;
        __syncthreads();
        sd[t] += x;
        __syncthreads();
    }
    int toff = sd[t] - run;
    #pragma unroll
    for (int j = 0; j < PER; ++j) {
        int idx = t * PER + j;
        if (idx < NBINS) { binptr[idx] = toff + v[j]; cursor[idx] = toff + v[j]; }
    }
    if (t == 255) binptr[NBINS] = E;
}

// ---------------- scatter edges to bins (sequential writes within bin) ----------------
// packed: bits 0..16 = col (<2^17), bits 17..22 = row_in_bin
__global__ __launch_bounds__(256)
void scatter_bins(const int* __restrict__ row, const int* __restrict__ col,
                  const float* __restrict__ vals, int* __restrict__ cursor,
                  int2* __restrict__ ep, int E)
{
    int e = blockIdx.x * 256 + threadIdx.x;
    if (e < E) {
        int r = row[e];
        int pos = atomicAdd(&cursor[r >> 6], 1);
        ep[pos] = make_int2(col[e] | ((r & 63) << 17), __float_as_int(vals[e]));
    }
}

// ---------------- SpMM via bins: workgroup per 64-row bin, LDS fp32 accumulate ----------------
// H is bf16 rows (64 uints = 128 features). 4 independent gathers in flight per wave.
template<bool RELU, bool OUTBF16>
__global__ __launch_bounds__(256)
void spmm_bin(const int* __restrict__ binptr, const int2* __restrict__ ep,
              const unsigned int* __restrict__ H, void* __restrict__ outv, int n)
{
    __shared__ float acc[64 * 128];        // 32 KB
    const int t    = threadIdx.x;
    const int lane = t & 63;
    const int wv   = t >> 6;
    const int bin  = blockIdx.x;

    #pragma unroll
    for (int i = 0; i < 32; ++i) acc[i * 256 + t] = 0.f;
    __syncthreads();

    const int s = binptr[bin], e = binptr[bin + 1];
    for (int p = s + wv * 4; p < e; p += 16) {
        int2 m0 = ep[p];
        int2 m1 = ep[p + 1];
        int2 m2 = ep[p + 2];
        int2 m3 = ep[p + 3];
        unsigned int h0 = H[(size_t)(m0.x & 0x1FFFF) * 64 + lane];
        unsigned int h1 = H[(size_t)(m1.x & 0x1FFFF) * 64 + lane];
        unsigned int h2 = H[(size_t)(m2.x & 0x1FFFF) * 64 + lane];
        unsigned int h3 = H[(size_t)(m3.x & 0x1FFFF) * 64 + lane];
        float v0 = __int_as_float(m0.y);                      // p < e always
        float v1 = (p + 1 < e) ? __int_as_float(m1.y) : 0.f;  // wave-uniform guards
        float v2 = (p + 2 < e) ? __int_as_float(m2.y) : 0.f;
        float v3 = (p + 3 < e) ? __int_as_float(m3.y) : 0.f;
        float* a0 = &acc[(m0.x >> 17) * 128 + lane * 2];
        float* a1 = &acc[(m1.x >> 17) * 128 + lane * 2];
        float* a2 = &acc[(m2.x >> 17) * 128 + lane * 2];
        float* a3 = &acc[(m3.x >> 17) * 128 + lane * 2];
        atomicAdd(a0,     v0 * __uint_as_float(h0 << 16));
        atomicAdd(a0 + 1, v0 * __uint_as_float(h0 & 0xffff0000u));
        atomicAdd(a1,     v1 * __uint_as_float(h1 << 16));
        atomicAdd(a1 + 1, v1 * __uint_as_float(h1 & 0xffff0000u));
        atomicAdd(a2,     v2 * __uint_as_float(h2 << 16));
        atomicAdd(a2 + 1, v2 * __uint_as_float(h2 & 0xffff0000u));
        atomicAdd(a3,     v3 * __uint_as_float(h3 << 16));
        atomicAdd(a3 + 1, v3 * __uint_as_float(h3 & 0xffff0000u));
    }
    __syncthreads();

    const int row0 = bin * 64;
    if (OUTBF16) {
        unsigned int* o = (unsigned int*)outv;
        #pragma unroll
        for (int i = 0; i < 16; ++i) {
            int idx = i * 256 + t;          // 4096 uints = 64 rows x 64
            int r = idx >> 6, cp = idx & 63;
            int gr = row0 + r;
            if (gr < n) {
                float2 xy = *(const float2*)&acc[r * 128 + cp * 2];
                if (RELU) { xy.x = fmaxf(xy.x, 0.f); xy.y = fmaxf(xy.y, 0.f); }
                o[(size_t)gr * 64 + cp] = (f2bf(xy.y) << 16) | f2bf(xy.x);
            }
        }
    } else {
        float2* o = (float2*)outv;
        #pragma unroll
        for (int i = 0; i < 16; ++i) {
            int idx = i * 256 + t;          // 4096 float2
            int r = idx >> 6, cp = idx & 63;
            int gr = row0 + r;
            if (gr < n) {
                float2 xy = *(const float2*)&acc[r * 128 + cp * 2];
                if (RELU) { xy.x = fmaxf(xy.x, 0.f); xy.y = fmaxf(xy.y, 0.f); }
                o[(size_t)gr * 64 + cp] = xy;
            }
        }
    }
}

// ---------------- launch ----------------
extern "C" void kernel_launch(void* const* d_in, const int* in_sizes, int n_in,
                              void* d_out, int out_size, void* d_ws, size_t ws_size,
                              hipStream_t stream)
{
    const float* X    = (const float*)d_in[0];
    const float* W1   = (const float*)d_in[1];
    const float* b1   = (const float*)d_in[2];
    const float* W2   = (const float*)d_in[3];
    const float* b2   = (const float*)d_in[4];
    const float* vals = (const float*)d_in[5];
    const int*   row  = (const int*)d_in[6];
    const int*   col  = (const int*)d_in[7];
    float* out = (float*)d_out;

    char* ws = (char*)d_ws;
    size_t off = 0;
    auto alloc = [&](size_t bytes) -> void* {
        void* p = ws + off;
        off += (bytes + 511) & ~(size_t)511;
        return p;
    };
    unsigned short* Y1     = (unsigned short*)alloc((size_t)N_NODES * 128 * 2); // bf16 Y1/Y2
    unsigned short* Hbuf   = (unsigned short*)alloc((size_t)N_NODES * 128 * 2); // bf16 relu(spmm1)
    int2*           ep     = (int2*) alloc((size_t)(N_EDGES + 4) * 8);
    int*            bincnt = (int*)  alloc((size_t)NBINS * 4);
    int*            binptr = (int*)  alloc((size_t)(NBINS + 1) * 4);
    int*            cursor = (int*)  alloc((size_t)NBINS * 4);
    unsigned short* W1t    = (unsigned short*)alloc((size_t)128 * 256 * 2);
    unsigned short* W2t    = (unsigned short*)alloc((size_t)128 * 128 * 2);

    conv_w<<<(256 * 128 + 128 * 128 + 255) / 256, 256, 0, stream>>>(W1, W2, W1t, W2t);

    // --- bin build ---
    hipMemsetAsync(bincnt, 0, (size_t)NBINS * 4, stream);
    hipMemsetAsync(ep + N_EDGES, 0, 4 * sizeof(int2), stream);  // pad for unroll-4 overread
    bin_hist<<<128, 256, 0, stream>>>(row, bincnt, N_EDGES);
    bin_scan<<<1, 256, 0, stream>>>(bincnt, binptr, cursor, N_EDGES);
    scatter_bins<<<(N_EDGES + 255) / 256, 256, 0, stream>>>(row, col, vals, cursor, ep, N_EDGES);

    // --- layer 1: Y1 = bf16(X@W1+b1) ; H = bf16(relu(A@Y1)) ---
    const int gblocks = (N_NODES + 127) / 128;
    gemm_mfma<256, false><<<gblocks, 256, 0, stream>>>(X, W1t, b1, Y1, N_NODES);
    spmm_bin<true, true><<<NBINS, 256, 0, stream>>>(binptr, ep, (const unsigned int*)Y1, Hbuf, N_NODES);

    // --- layer 2: Y2 = bf16(H@W2+b2) ; out = A@Y2 (fp32) ---
    gemm_mfma<128, true><<<gblocks, 256, 0, stream>>>(Hbuf, W2t, b2, Y1, N_NODES);
    spmm_bin<false, false><<<NBINS, 256, 0, stream>>>(binptr, ep, (const unsigned int*)Y1, out, N_NODES);
}

// Round 5
// 625.138 us; speedup vs baseline: 4.4969x; 4.4969x over previous
//
#include <hip/hip_runtime.h>

#define N_NODES 100000
#define N_EDGES 1600000
#define NBINS 1563   // ceil(N_NODES/64)

typedef __attribute__((ext_vector_type(8))) short bf16x8;
typedef __attribute__((ext_vector_type(4))) float f32x4;

__device__ __forceinline__ unsigned int f2bf(float f) {
    unsigned int u = __float_as_uint(f);
    u += 0x7fffu + ((u >> 16) & 1u);     // RNE (finite normals)
    return u >> 16;
}
__device__ __forceinline__ float bflo(unsigned int h) { return __uint_as_float(h << 16); }
__device__ __forceinline__ float bfhi(unsigned int h) { return __uint_as_float(h & 0xffff0000u); }

// ---------------- weight convert+transpose: Wt[n][k] = bf16(W[k][n]) ----------------
__global__ __launch_bounds__(256)
void conv_w(const float* __restrict__ W1, const float* __restrict__ W2,
            unsigned short* __restrict__ W1t, unsigned short* __restrict__ W2t)
{
    int idx = blockIdx.x * 256 + threadIdx.x;
    if (idx < 256 * 128) {
        int k = idx >> 7, n = idx & 127;
        W1t[(size_t)n * 256 + k] = (unsigned short)f2bf(W1[idx]);
    } else if (idx < 256 * 128 + 128 * 128) {
        int j = idx - 256 * 128;
        int k = j >> 7, n = j & 127;
        W2t[(size_t)n * 128 + k] = (unsigned short)f2bf(W2[j]);
    }
}

// ---------------- MFMA GEMM: C[M x 128] = A[M x K] @ W[K x 128] + bias, C bf16 ----------------
template<int K, bool ABF16>
__global__ __launch_bounds__(256, 3)
void gemm_mfma(const void* __restrict__ Av, const unsigned short* __restrict__ Wt,
               const float* __restrict__ bias, unsigned short* __restrict__ C, int M)
{
    constexpr int BK = 64;
    constexpr int PK = BK + 8;                 // 144 B pitch: 2-way banks max (free)
    __shared__ unsigned short As[128 * PK];
    __shared__ unsigned short Bs[128 * PK];

    const int t    = threadIdx.x;
    const int m0   = blockIdx.x * 128;
    const int lane = t & 63;
    const int wv   = t >> 6;
    const int wm   = (wv >> 1) * 64;
    const int wn   = (wv & 1) * 64;
    const int l15  = lane & 15;
    const int quad = lane >> 4;

    f32x4 acc[4][4] = {};

    for (int k0 = 0; k0 < K; k0 += BK) {
        if (!ABF16) {
            const float* A = (const float*)Av;
            #pragma unroll
            for (int p = 0; p < 8; ++p) {
                int q  = p * 256 + t;
                int m  = q >> 4;
                int kq = (q & 15) << 2;
                int gm = m0 + m; if (gm >= M) gm = M - 1;
                float4 v = *(const float4*)(A + (size_t)gm * K + k0 + kq);
                unsigned int p0 = (f2bf(v.y) << 16) | f2bf(v.x);
                unsigned int p1 = (f2bf(v.w) << 16) | f2bf(v.z);
                *(uint2*)&As[m * PK + kq] = make_uint2(p0, p1);
            }
        } else {
            const unsigned short* A = (const unsigned short*)Av;
            #pragma unroll
            for (int p = 0; p < 4; ++p) {
                int q = p * 256 + t;
                int m = q >> 3;
                int g = q & 7;
                int gm = m0 + m; if (gm >= M) gm = M - 1;
                int4 v = *(const int4*)(A + (size_t)gm * K + k0 + g * 8);
                *(int4*)&As[m * PK + g * 8] = v;
            }
        }
        #pragma unroll
        for (int p = 0; p < 4; ++p) {
            int q = p * 256 + t;
            int n = q >> 3;
            int g = q & 7;
            int4 v = *(const int4*)(Wt + (size_t)n * K + k0 + g * 8);
            *(int4*)&Bs[n * PK + g * 8] = v;
        }
        __syncthreads();
        #pragma unroll
        for (int kk = 0; kk < BK; kk += 32) {
            bf16x8 a[4], b[4];
            #pragma unroll
            for (int i = 0; i < 4; ++i)
                a[i] = *(const bf16x8*)&As[(wm + i * 16 + l15) * PK + kk + quad * 8];
            #pragma unroll
            for (int j = 0; j < 4; ++j)
                b[j] = *(const bf16x8*)&Bs[(wn + j * 16 + l15) * PK + kk + quad * 8];
            #pragma unroll
            for (int i = 0; i < 4; ++i)
                #pragma unroll
                for (int j = 0; j < 4; ++j)
                    acc[i][j] = __builtin_amdgcn_mfma_f32_16x16x32_bf16(a[i], b[j], acc[i][j], 0, 0, 0);
        }
        __syncthreads();
    }

    float bv[4];
    #pragma unroll
    for (int j = 0; j < 4; ++j) bv[j] = bias[wn + j * 16 + l15];
    #pragma unroll
    for (int i = 0; i < 4; ++i) {
        #pragma unroll
        for (int r = 0; r < 4; ++r) {
            int gm = m0 + wm + i * 16 + quad * 4 + r;
            if (gm < M) {
                #pragma unroll
                for (int j = 0; j < 4; ++j)
                    C[(size_t)gm * 128 + wn + j * 16 + l15] =
                        (unsigned short)f2bf(acc[i][j][r] + bv[j]);
            }
        }
    }
}

// ---------------- bin histogram (bin = row>>6), per-block LDS ----------------
__global__ __launch_bounds__(256)
void bin_hist(const int* __restrict__ row, int* __restrict__ bincnt, int E)
{
    __shared__ int h[NBINS];
    int t = threadIdx.x;
    for (int i = t; i < NBINS; i += 256) h[i] = 0;
    __syncthreads();
    for (int e = blockIdx.x * 256 + t; e < E; e += gridDim.x * 256)
        atomicAdd(&h[row[e] >> 6], 1);
    __syncthreads();
    for (int i = t; i < NBINS; i += 256) {
        int v = h[i];
        if (v) atomicAdd(&bincnt[i], v);
    }
}

// ---------------- exclusive scan over NBINS (single block) ----------------
__global__ __launch_bounds__(256)
void bin_scan(const int* __restrict__ bincnt, int* __restrict__ binptr,
              int* __restrict__ cursor, int* __restrict__ rowptr, int E)
{
    __shared__ int sd[256];
    const int PER = (NBINS + 255) / 256;   // 7
    int t = threadIdx.x;
    int v[PER]; int run = 0;
    #pragma unroll
    for (int j = 0; j < PER; ++j) {
        int idx = t * PER + j;
        int c = (idx < NBINS) ? bincnt[idx] : 0;
        v[j] = run; run += c;
    }
    sd[t] = run;
    __syncthreads();
    for (int off = 1; off < 256; off <<= 1) {
        int x = (t >= off) ? sd[t - off] : 0;
        __syncthreads();
        sd[t] += x;
        __syncthreads();
    }
    int toff = sd[t] - run;
    #pragma unroll
    for (int j = 0; j < PER; ++j) {
        int idx = t * PER + j;
        if (idx < NBINS) { binptr[idx] = toff + v[j]; cursor[idx] = toff + v[j]; }
    }
    if (t == 255) { binptr[NBINS] = E; rowptr[N_NODES] = E; }
}

// ---------------- scatter edges to bins (sequential writes within bin window) ----------------
// packed: bits 0..16 = col (<2^17), bits 17..22 = row_in_bin
__global__ __launch_bounds__(256)
void scatter_bins(const int* __restrict__ row, const int* __restrict__ col,
                  const float* __restrict__ vals, int* __restrict__ cursor,
                  int2* __restrict__ ep, int E)
{
    int e = blockIdx.x * 256 + threadIdx.x;
    if (e < E) {
        int r = row[e];
        int pos = atomicAdd(&cursor[r >> 6], 1);
        ep[pos] = make_int2(col[e] | ((r & 63) << 17), __float_as_int(vals[e]));
    }
}

// ---------------- intra-bin counting sort -> row-sorted ep2 + rowptr ----------------
// one block per bin; 64-row LDS histogram, wave scan, re-scatter (any bin size).
__global__ __launch_bounds__(256)
void sort_bin(const int2* __restrict__ ep, int2* __restrict__ ep2,
              const int* __restrict__ binptr, int* __restrict__ rowptr, int n)
{
    __shared__ int cnt[64];
    __shared__ int cur[64];
    const int t   = threadIdx.x;
    const int bin = blockIdx.x;
    const int s = binptr[bin], e = binptr[bin + 1];

    if (t < 64) cnt[t] = 0;
    __syncthreads();
    for (int p = s + t; p < e; p += 256)
        atomicAdd(&cnt[(unsigned)ep[p].x >> 17], 1);
    __syncthreads();
    if (t < 64) {
        int c = cnt[t];
        int incl = c;
        #pragma unroll
        for (int o = 1; o < 64; o <<= 1) {      // wave-level inclusive scan
            int u = __shfl_up(incl, o, 64);
            if (t >= o) incl += u;
        }
        int base = s + incl - c;                 // exclusive
        cur[t] = base;
        int gr = bin * 64 + t;
        if (gr < n) rowptr[gr] = base;
    }
    __syncthreads();
    for (int p = s + t; p < e; p += 256) {
        int2 m = ep[p];
        int pos = atomicAdd(&cur[(unsigned)m.x >> 17], 1);
        ep2[pos] = m;
    }
}

// ---------------- SpMM (pull, row-sorted, bf16 H): one wave per node, unroll 8 ----------------
template<bool RELU, bool OUTBF16>
__global__ __launch_bounds__(256)
void spmm_csr(const int* __restrict__ rowptr, const int2* __restrict__ ep,
              const unsigned int* __restrict__ H, void* __restrict__ outv, int n)
{
    int wid  = (blockIdx.x * 256 + threadIdx.x) >> 6;
    int lane = threadIdx.x & 63;
    if (wid >= n) return;
    const int s = rowptr[wid], e = rowptr[wid + 1];

    float ax0 = 0.f, ay0 = 0.f, ax1 = 0.f, ay1 = 0.f;
    float ax2 = 0.f, ay2 = 0.f, ax3 = 0.f, ay3 = 0.f;

    for (int p = s; p < e; p += 8) {
        int2 m0 = ep[p],     m1 = ep[p + 1], m2 = ep[p + 2], m3 = ep[p + 3];
        int2 m4 = ep[p + 4], m5 = ep[p + 5], m6 = ep[p + 6], m7 = ep[p + 7];
        // tail-masked cols -> overread gathers collapse to one cached line
        int c0 = m0.x & 0x1FFFF;
        int c1 = (p + 1 < e) ? (m1.x & 0x1FFFF) : 0;
        int c2 = (p + 2 < e) ? (m2.x & 0x1FFFF) : 0;
        int c3 = (p + 3 < e) ? (m3.x & 0x1FFFF) : 0;
        int c4 = (p + 4 < e) ? (m4.x & 0x1FFFF) : 0;
        int c5 = (p + 5 < e) ? (m5.x & 0x1FFFF) : 0;
        int c6 = (p + 6 < e) ? (m6.x & 0x1FFFF) : 0;
        int c7 = (p + 7 < e) ? (m7.x & 0x1FFFF) : 0;
        unsigned int h0 = H[(size_t)c0 * 64 + lane];
        unsigned int h1 = H[(size_t)c1 * 64 + lane];
        unsigned int h2 = H[(size_t)c2 * 64 + lane];
        unsigned int h3 = H[(size_t)c3 * 64 + lane];
        unsigned int h4 = H[(size_t)c4 * 64 + lane];
        unsigned int h5 = H[(size_t)c5 * 64 + lane];
        unsigned int h6 = H[(size_t)c6 * 64 + lane];
        unsigned int h7 = H[(size_t)c7 * 64 + lane];
        float v0 = __int_as_float(m0.y);
        float v1 = (p + 1 < e) ? __int_as_float(m1.y) : 0.f;
        float v2 = (p + 2 < e) ? __int_as_float(m2.y) : 0.f;
        float v3 = (p + 3 < e) ? __int_as_float(m3.y) : 0.f;
        float v4 = (p + 4 < e) ? __int_as_float(m4.y) : 0.f;
        float v5 = (p + 5 < e) ? __int_as_float(m5.y) : 0.f;
        float v6 = (p + 6 < e) ? __int_as_float(m6.y) : 0.f;
        float v7 = (p + 7 < e) ? __int_as_float(m7.y) : 0.f;
        ax0 = fmaf(v0, bflo(h0), ax0); ay0 = fmaf(v0, bfhi(h0), ay0);
        ax1 = fmaf(v1, bflo(h1), ax1); ay1 = fmaf(v1, bfhi(h1), ay1);
        ax2 = fmaf(v2, bflo(h2), ax2); ay2 = fmaf(v2, bfhi(h2), ay2);
        ax3 = fmaf(v3, bflo(h3), ax3); ay3 = fmaf(v3, bfhi(h3), ay3);
        ax0 = fmaf(v4, bflo(h4), ax0); ay0 = fmaf(v4, bfhi(h4), ay0);
        ax1 = fmaf(v5, bflo(h5), ax1); ay1 = fmaf(v5, bfhi(h5), ay1);
        ax2 = fmaf(v6, bflo(h6), ax2); ay2 = fmaf(v6, bfhi(h6), ay2);
        ax3 = fmaf(v7, bflo(h7), ax3); ay3 = fmaf(v7, bfhi(h7), ay3);
    }
    float ax = (ax0 + ax1) + (ax2 + ax3);
    float ay = (ay0 + ay1) + (ay2 + ay3);
    if (RELU) { ax = fmaxf(ax, 0.f); ay = fmaxf(ay, 0.f); }
    if (OUTBF16) {
        ((unsigned int*)outv)[(size_t)wid * 64 + lane] = (f2bf(ay) << 16) | f2bf(ax);
    } else {
        ((float2*)outv)[(size_t)wid * 64 + lane] = make_float2(ax, ay);
    }
}

// ---------------- launch ----------------
extern "C" void kernel_launch(void* const* d_in, const int* in_sizes, int n_in,
                              void* d_out, int out_size, void* d_ws, size_t ws_size,
                              hipStream_t stream)
{
    const float* X    = (const float*)d_in[0];
    const float* W1   = (const float*)d_in[1];
    const float* b1   = (const float*)d_in[2];
    const float* W2   = (const float*)d_in[3];
    const float* b2   = (const float*)d_in[4];
    const float* vals = (const float*)d_in[5];
    const int*   row  = (const int*)d_in[6];
    const int*   col  = (const int*)d_in[7];
    float* out = (float*)d_out;

    char* ws = (char*)d_ws;
    size_t off = 0;
    auto alloc = [&](size_t bytes) -> void* {
        void* p = ws + off;
        off += (bytes + 511) & ~(size_t)511;
        return p;
    };
    unsigned short* Y1     = (unsigned short*)alloc((size_t)N_NODES * 128 * 2); // bf16 Y1/Y2
    unsigned short* Hbuf   = (unsigned short*)alloc((size_t)N_NODES * 128 * 2); // bf16 relu(spmm1)
    int2*           ep     = (int2*) alloc((size_t)(N_EDGES + 8) * 8);
    int2*           ep2    = (int2*) alloc((size_t)(N_EDGES + 8) * 8);
    int*            bincnt = (int*)  alloc((size_t)NBINS * 4);
    int*            binptr = (int*)  alloc((size_t)(NBINS + 1) * 4);
    int*            cursor = (int*)  alloc((size_t)NBINS * 4);
    int*            rowptr = (int*)  alloc((size_t)(N_NODES + 1) * 4);
    unsigned short* W1t    = (unsigned short*)alloc((size_t)128 * 256 * 2);
    unsigned short* W2t    = (unsigned short*)alloc((size_t)128 * 128 * 2);

    conv_w<<<(256 * 128 + 128 * 128 + 255) / 256, 256, 0, stream>>>(W1, W2, W1t, W2t);

    // --- edge build: bin scatter + intra-bin counting sort -> per-row CSR ---
    hipMemsetAsync(bincnt, 0, (size_t)NBINS * 4, stream);
    hipMemsetAsync(ep2 + N_EDGES, 0, 8 * sizeof(int2), stream);  // pad for unroll-8 overread
    bin_hist<<<128, 256, 0, stream>>>(row, bincnt, N_EDGES);
    bin_scan<<<1, 256, 0, stream>>>(bincnt, binptr, cursor, rowptr, N_EDGES);
    scatter_bins<<<(N_EDGES + 255) / 256, 256, 0, stream>>>(row, col, vals, cursor, ep, N_EDGES);
    sort_bin<<<NBINS, 256, 0, stream>>>(ep, ep2, binptr, rowptr, N_NODES);

    // --- layer 1: Y1 = bf16(X@W1+b1) ; H = bf16(relu(A@Y1)) ---
    const int gblocks = (N_NODES + 127) / 128;
    gemm_mfma<256, false><<<gblocks, 256, 0, stream>>>(X, W1t, b1, Y1, N_NODES);
    spmm_csr<true, true><<<(N_NODES + 3) / 4, 256, 0, stream>>>(rowptr, ep2, (const unsigned int*)Y1, Hbuf, N_NODES);

    // --- layer 2: Y2 = bf16(H@W2+b2) ; out = A@Y2 (fp32) ---
    gemm_mfma<128, true><<<gblocks, 256, 0, stream>>>(Hbuf, W2t, b2, Y1, N_NODES);
    spmm_csr<false, false><<<(N_NODES + 3) / 4, 256, 0, stream>>>(rowptr, ep2, (const unsigned int*)Y1, out, N_NODES);
}

// Round 6
// 438.757 us; speedup vs baseline: 6.4072x; 1.4248x over previous
//
#include <hip/hip_runtime.h>

#define N_NODES 100000
#define N_EDGES 1600000
#define NBINS 1563   // ceil(N_NODES/64)
#define CHUNK 8192
#define NBLK 196     // ceil(N_EDGES/CHUNK)

typedef __attribute__((ext_vector_type(8))) short bf16x8;
typedef __attribute__((ext_vector_type(4))) float f32x4;

__device__ __forceinline__ unsigned int f2bf(float f) {
    unsigned int u = __float_as_uint(f);
    u += 0x7fffu + ((u >> 16) & 1u);     // RNE (finite normals)
    return u >> 16;
}
__device__ __forceinline__ float bflo(unsigned int h) { return __uint_as_float(h << 16); }
__device__ __forceinline__ float bfhi(unsigned int h) { return __uint_as_float(h & 0xffff0000u); }

// ---------------- weight convert+transpose: Wt[n][k] = bf16(W[k][n]) ----------------
__global__ __launch_bounds__(256)
void conv_w(const float* __restrict__ W1, const float* __restrict__ W2,
            unsigned short* __restrict__ W1t, unsigned short* __restrict__ W2t)
{
    int idx = blockIdx.x * 256 + threadIdx.x;
    if (idx < 256 * 128) {
        int k = idx >> 7, n = idx & 127;
        W1t[(size_t)n * 256 + k] = (unsigned short)f2bf(W1[idx]);
    } else if (idx < 256 * 128 + 128 * 128) {
        int j = idx - 256 * 128;
        int k = j >> 7, n = j & 127;
        W2t[(size_t)n * 128 + k] = (unsigned short)f2bf(W2[j]);
    }
}

// ---------------- MFMA GEMM: C[M x 128] = A[M x K] @ W[K x 128] + bias, C bf16 ----------------
template<int K, bool ABF16>
__global__ __launch_bounds__(256, 3)
void gemm_mfma(const void* __restrict__ Av, const unsigned short* __restrict__ Wt,
               const float* __restrict__ bias, unsigned short* __restrict__ C, int M)
{
    constexpr int BK = 64;
    constexpr int PK = BK + 8;                 // 144 B pitch: 2-way banks max (free)
    __shared__ unsigned short As[128 * PK];
    __shared__ unsigned short Bs[128 * PK];

    const int t    = threadIdx.x;
    const int m0   = blockIdx.x * 128;
    const int lane = t & 63;
    const int wv   = t >> 6;
    const int wm   = (wv >> 1) * 64;
    const int wn   = (wv & 1) * 64;
    const int l15  = lane & 15;
    const int quad = lane >> 4;

    f32x4 acc[4][4] = {};

    for (int k0 = 0; k0 < K; k0 += BK) {
        if (!ABF16) {
            const float* A = (const float*)Av;
            #pragma unroll
            for (int p = 0; p < 8; ++p) {
                int q  = p * 256 + t;
                int m  = q >> 4;
                int kq = (q & 15) << 2;
                int gm = m0 + m; if (gm >= M) gm = M - 1;
                float4 v = *(const float4*)(A + (size_t)gm * K + k0 + kq);
                unsigned int p0 = (f2bf(v.y) << 16) | f2bf(v.x);
                unsigned int p1 = (f2bf(v.w) << 16) | f2bf(v.z);
                *(uint2*)&As[m * PK + kq] = make_uint2(p0, p1);
            }
        } else {
            const unsigned short* A = (const unsigned short*)Av;
            #pragma unroll
            for (int p = 0; p < 4; ++p) {
                int q = p * 256 + t;
                int m = q >> 3;
                int g = q & 7;
                int gm = m0 + m; if (gm >= M) gm = M - 1;
                int4 v = *(const int4*)(A + (size_t)gm * K + k0 + g * 8);
                *(int4*)&As[m * PK + g * 8] = v;
            }
        }
        #pragma unroll
        for (int p = 0; p < 4; ++p) {
            int q = p * 256 + t;
            int n = q >> 3;
            int g = q & 7;
            int4 v = *(const int4*)(Wt + (size_t)n * K + k0 + g * 8);
            *(int4*)&Bs[n * PK + g * 8] = v;
        }
        __syncthreads();
        #pragma unroll
        for (int kk = 0; kk < BK; kk += 32) {
            bf16x8 a[4], b[4];
            #pragma unroll
            for (int i = 0; i < 4; ++i)
                a[i] = *(const bf16x8*)&As[(wm + i * 16 + l15) * PK + kk + quad * 8];
            #pragma unroll
            for (int j = 0; j < 4; ++j)
                b[j] = *(const bf16x8*)&Bs[(wn + j * 16 + l15) * PK + kk + quad * 8];
            #pragma unroll
            for (int i = 0; i < 4; ++i)
                #pragma unroll
                for (int j = 0; j < 4; ++j)
                    acc[i][j] = __builtin_amdgcn_mfma_f32_16x16x32_bf16(a[i], b[j], acc[i][j], 0, 0, 0);
        }
        __syncthreads();
    }

    float bv[4];
    #pragma unroll
    for (int j = 0; j < 4; ++j) bv[j] = bias[wn + j * 16 + l15];
    #pragma unroll
    for (int i = 0; i < 4; ++i) {
        #pragma unroll
        for (int r = 0; r < 4; ++r) {
            int gm = m0 + wm + i * 16 + quad * 4 + r;
            if (gm < M) {
                #pragma unroll
                for (int j = 0; j < 4; ++j)
                    C[(size_t)gm * 128 + wn + j * 16 + l15] =
                        (unsigned short)f2bf(acc[i][j][r] + bv[j]);
            }
        }
    }
}

// ---------------- counting sort K1: per-chunk LDS histogram -> hist[blk][bin] ----------------
__global__ __launch_bounds__(256)
void hist_block(const int* __restrict__ row, int* __restrict__ hist, int E)
{
    __shared__ int h[NBINS];
    const int t = threadIdx.x, b = blockIdx.x;
    for (int i = t; i < NBINS; i += 256) h[i] = 0;
    __syncthreads();
    const int s = b * CHUNK, e = min(E, s + CHUNK);
    for (int p = s + t; p < e; p += 256)
        atomicAdd(&h[row[p] >> 6], 1);
    __syncthreads();
    for (int i = t; i < NBINS; i += 256)
        hist[(size_t)b * NBINS + i] = h[i];
}

// ---------------- counting sort K2: exclusive scan down each bin's column; totals -> bincnt ----
__global__ __launch_bounds__(256)
void scan_cols(int* __restrict__ hist, int* __restrict__ bincnt, int nblk)
{
    int bin  = (blockIdx.x * 256 + threadIdx.x) >> 6;
    int lane = threadIdx.x & 63;
    if (bin >= NBINS) return;
    int run = 0;
    for (int r0 = 0; r0 < nblk; r0 += 64) {
        int idx = r0 + lane;
        int v = (idx < nblk) ? hist[(size_t)idx * NBINS + bin] : 0;
        int incl = v;
        #pragma unroll
        for (int o = 1; o < 64; o <<= 1) {
            int u = __shfl_up(incl, o, 64);
            if (lane >= o) incl += u;
        }
        if (idx < nblk) hist[(size_t)idx * NBINS + bin] = run + incl - v;
        run += __shfl(incl, 63, 64);
    }
    if (lane == 0) bincnt[bin] = run;
}

// ---------------- counting sort K3: exclusive scan over NBINS (single block) ----------------
__global__ __launch_bounds__(256)
void bin_scan(const int* __restrict__ bincnt, int* __restrict__ binptr,
              int* __restrict__ rowptr, int E)
{
    __shared__ int sd[256];
    const int PER = (NBINS + 255) / 256;   // 7
    int t = threadIdx.x;
    int v[PER]; int run = 0;
    #pragma unroll
    for (int j = 0; j < PER; ++j) {
        int idx = t * PER + j;
        int c = (idx < NBINS) ? bincnt[idx] : 0;
        v[j] = run; run += c;
    }
    sd[t] = run;
    __syncthreads();
    for (int off = 1; off < 256; off <<= 1) {
        int x = (t >= off) ? sd[t - off] : 0;
        __syncthreads();
        sd[t] += x;
        __syncthreads();
    }
    int toff = sd[t] - run;
    #pragma unroll
    for (int j = 0; j < PER; ++j) {
        int idx = t * PER + j;
        if (idx < NBINS) binptr[idx] = toff + v[j];
    }
    if (t == 255) { binptr[NBINS] = E; rowptr[N_NODES] = E; }
}

// ---------------- counting sort K4: scatter into deterministic per-(block,bin) windows --------
// LDS cursors only; zero global atomics. packed: bits 0..16 = col, bits 17..22 = row_in_bin
__global__ __launch_bounds__(256)
void scatter_bins(const int* __restrict__ row, const int* __restrict__ col,
                  const float* __restrict__ vals, const int* __restrict__ binptr,
                  const int* __restrict__ hist, int2* __restrict__ ep, int E)
{
    __shared__ int cur[NBINS];
    const int t = threadIdx.x, b = blockIdx.x;
    for (int i = t; i < NBINS; i += 256)
        cur[i] = binptr[i] + hist[(size_t)b * NBINS + i];
    __syncthreads();
    const int s = b * CHUNK, e = min(E, s + CHUNK);
    for (int p = s + t; p < e; p += 256) {
        int r = row[p];
        int pos = atomicAdd(&cur[r >> 6], 1);   // LDS atomic (native ds_add_rtn)
        ep[pos] = make_int2(col[p] | ((r & 63) << 17), __float_as_int(vals[p]));
    }
}

// ---------------- intra-bin counting sort -> row-sorted ep2 + rowptr ----------------
__global__ __launch_bounds__(256)
void sort_bin(const int2* __restrict__ ep, int2* __restrict__ ep2,
              const int* __restrict__ binptr, int* __restrict__ rowptr, int n)
{
    __shared__ int cnt[64];
    __shared__ int cur[64];
    const int t   = threadIdx.x;
    const int bin = blockIdx.x;
    const int s = binptr[bin], e = binptr[bin + 1];

    if (t < 64) cnt[t] = 0;
    __syncthreads();
    for (int p = s + t; p < e; p += 256)
        atomicAdd(&cnt[(unsigned)ep[p].x >> 17], 1);
    __syncthreads();
    if (t < 64) {
        int c = cnt[t];
        int incl = c;
        #pragma unroll
        for (int o = 1; o < 64; o <<= 1) {
            int u = __shfl_up(incl, o, 64);
            if (t >= o) incl += u;
        }
        int base = s + incl - c;
        cur[t] = base;
        int gr = bin * 64 + t;
        if (gr < n) rowptr[gr] = base;
    }
    __syncthreads();
    for (int p = s + t; p < e; p += 256) {
        int2 m = ep[p];
        int pos = atomicAdd(&cur[(unsigned)m.x >> 17], 1);
        ep2[pos] = m;
    }
}

// ---------------- SpMM (pull, row-sorted, bf16 H): one wave per node, unroll 8 ----------------
template<bool RELU, bool OUTBF16>
__global__ __launch_bounds__(256)
void spmm_csr(const int* __restrict__ rowptr, const int2* __restrict__ ep,
              const unsigned int* __restrict__ H, void* __restrict__ outv, int n)
{
    int wid  = (blockIdx.x * 256 + threadIdx.x) >> 6;
    int lane = threadIdx.x & 63;
    if (wid >= n) return;
    const int s = rowptr[wid], e = rowptr[wid + 1];

    float ax0 = 0.f, ay0 = 0.f, ax1 = 0.f, ay1 = 0.f;
    float ax2 = 0.f, ay2 = 0.f, ax3 = 0.f, ay3 = 0.f;

    for (int p = s; p < e; p += 8) {
        int2 m0 = ep[p],     m1 = ep[p + 1], m2 = ep[p + 2], m3 = ep[p + 3];
        int2 m4 = ep[p + 4], m5 = ep[p + 5], m6 = ep[p + 6], m7 = ep[p + 7];
        int c0 = m0.x & 0x1FFFF;
        int c1 = (p + 1 < e) ? (m1.x & 0x1FFFF) : 0;
        int c2 = (p + 2 < e) ? (m2.x & 0x1FFFF) : 0;
        int c3 = (p + 3 < e) ? (m3.x & 0x1FFFF) : 0;
        int c4 = (p + 4 < e) ? (m4.x & 0x1FFFF) : 0;
        int c5 = (p + 5 < e) ? (m5.x & 0x1FFFF) : 0;
        int c6 = (p + 6 < e) ? (m6.x & 0x1FFFF) : 0;
        int c7 = (p + 7 < e) ? (m7.x & 0x1FFFF) : 0;
        unsigned int h0 = H[(size_t)c0 * 64 + lane];
        unsigned int h1 = H[(size_t)c1 * 64 + lane];
        unsigned int h2 = H[(size_t)c2 * 64 + lane];
        unsigned int h3 = H[(size_t)c3 * 64 + lane];
        unsigned int h4 = H[(size_t)c4 * 64 + lane];
        unsigned int h5 = H[(size_t)c5 * 64 + lane];
        unsigned int h6 = H[(size_t)c6 * 64 + lane];
        unsigned int h7 = H[(size_t)c7 * 64 + lane];
        float v0 = __int_as_float(m0.y);
        float v1 = (p + 1 < e) ? __int_as_float(m1.y) : 0.f;
        float v2 = (p + 2 < e) ? __int_as_float(m2.y) : 0.f;
        float v3 = (p + 3 < e) ? __int_as_float(m3.y) : 0.f;
        float v4 = (p + 4 < e) ? __int_as_float(m4.y) : 0.f;
        float v5 = (p + 5 < e) ? __int_as_float(m5.y) : 0.f;
        float v6 = (p + 6 < e) ? __int_as_float(m6.y) : 0.f;
        float v7 = (p + 7 < e) ? __int_as_float(m7.y) : 0.f;
        ax0 = fmaf(v0, bflo(h0), ax0); ay0 = fmaf(v0, bfhi(h0), ay0);
        ax1 = fmaf(v1, bflo(h1), ax1); ay1 = fmaf(v1, bfhi(h1), ay1);
        ax2 = fmaf(v2, bflo(h2), ax2); ay2 = fmaf(v2, bfhi(h2), ay2);
        ax3 = fmaf(v3, bflo(h3), ax3); ay3 = fmaf(v3, bfhi(h3), ay3);
        ax0 = fmaf(v4, bflo(h4), ax0); ay0 = fmaf(v4, bfhi(h4), ay0);
        ax1 = fmaf(v5, bflo(h5), ax1); ay1 = fmaf(v5, bfhi(h5), ay1);
        ax2 = fmaf(v6, bflo(h6), ax2); ay2 = fmaf(v6, bfhi(h6), ay2);
        ax3 = fmaf(v7, bflo(h7), ax3); ay3 = fmaf(v7, bfhi(h7), ay3);
    }
    float ax = (ax0 + ax1) + (ax2 + ax3);
    float ay = (ay0 + ay1) + (ay2 + ay3);
    if (RELU) { ax = fmaxf(ax, 0.f); ay = fmaxf(ay, 0.f); }
    if (OUTBF16) {
        ((unsigned int*)outv)[(size_t)wid * 64 + lane] = (f2bf(ay) << 16) | f2bf(ax);
    } else {
        ((float2*)outv)[(size_t)wid * 64 + lane] = make_float2(ax, ay);
    }
}

// ---------------- launch ----------------
extern "C" void kernel_launch(void* const* d_in, const int* in_sizes, int n_in,
                              void* d_out, int out_size, void* d_ws, size_t ws_size,
                              hipStream_t stream)
{
    const float* X    = (const float*)d_in[0];
    const float* W1   = (const float*)d_in[1];
    const float* b1   = (const float*)d_in[2];
    const float* W2   = (const float*)d_in[3];
    const float* b2   = (const float*)d_in[4];
    const float* vals = (const float*)d_in[5];
    const int*   row  = (const int*)d_in[6];
    const int*   col  = (const int*)d_in[7];
    float* out = (float*)d_out;

    char* ws = (char*)d_ws;
    size_t off = 0;
    auto alloc = [&](size_t bytes) -> void* {
        void* p = ws + off;
        off += (bytes + 511) & ~(size_t)511;
        return p;
    };
    unsigned short* Y1     = (unsigned short*)alloc((size_t)N_NODES * 128 * 2); // bf16 Y1/Y2
    unsigned short* Hbuf   = (unsigned short*)alloc((size_t)N_NODES * 128 * 2); // bf16 relu(spmm1)
    int2*           ep     = (int2*) alloc((size_t)(N_EDGES + 8) * 8);
    int2*           ep2    = (int2*) alloc((size_t)(N_EDGES + 8) * 8);
    int*            hist   = (int*)  alloc((size_t)NBLK * NBINS * 4);   // 1.23 MB
    int*            bincnt = (int*)  alloc((size_t)NBINS * 4);
    int*            binptr = (int*)  alloc((size_t)(NBINS + 1) * 4);
    int*            rowptr = (int*)  alloc((size_t)(N_NODES + 1) * 4);
    unsigned short* W1t    = (unsigned short*)alloc((size_t)128 * 256 * 2);
    unsigned short* W2t    = (unsigned short*)alloc((size_t)128 * 128 * 2);

    conv_w<<<(256 * 128 + 128 * 128 + 255) / 256, 256, 0, stream>>>(W1, W2, W1t, W2t);

    // --- edge build: deterministic two-level counting sort -> per-row CSR, no global atomics ---
    hipMemsetAsync(ep2 + N_EDGES, 0, 8 * sizeof(int2), stream);  // pad for unroll-8 overread
    hist_block<<<NBLK, 256, 0, stream>>>(row, hist, N_EDGES);
    scan_cols<<<(NBINS * 64 + 255) / 256, 256, 0, stream>>>(hist, bincnt, NBLK);
    bin_scan<<<1, 256, 0, stream>>>(bincnt, binptr, rowptr, N_EDGES);
    scatter_bins<<<NBLK, 256, 0, stream>>>(row, col, vals, binptr, hist, ep, N_EDGES);
    sort_bin<<<NBINS, 256, 0, stream>>>(ep, ep2, binptr, rowptr, N_NODES);

    // --- layer 1: Y1 = bf16(X@W1+b1) ; H = bf16(relu(A@Y1)) ---
    const int gblocks = (N_NODES + 127) / 128;
    gemm_mfma<256, false><<<gblocks, 256, 0, stream>>>(X, W1t, b1, Y1, N_NODES);
    spmm_csr<true, true><<<(N_NODES + 3) / 4, 256, 0, stream>>>(rowptr, ep2, (const unsigned int*)Y1, Hbuf, N_NODES);

    // --- layer 2: Y2 = bf16(H@W2+b2) ; out = A@Y2 (fp32) ---
    gemm_mfma<128, true><<<gblocks, 256, 0, stream>>>(Hbuf, W2t, b2, Y1, N_NODES);
    spmm_csr<false, false><<<(N_NODES + 3) / 4, 256, 0, stream>>>(rowptr, ep2, (const unsigned int*)Y1, out, N_NODES);
}